// Round 1
// 280.264 us; speedup vs baseline: 1.0319x; 1.0319x over previous
//
#include <hip/hip_runtime.h>

// TreeAttentionV2: B=8, T=1024, C=1024 (L=4,R=256), H=16, hd=64.
// Pipeline (all fp16 MFMA, fp32 accumulate):
//   1. conv_x:    x fp32 (8192x1024) -> xh fp16
//   2. tconv x2:  w_attn -> waT fp16 (3072x1024), w_proj -> wpT fp16 (1024x1024)
//   3. gemm8p<split3>: qn/kn/vn = xh @ waT^T + b_attn (8-phase pipelined, see below)
//   4. pack_k:    kn -> kP, MFMA-A-fragment order
//   5. pack_v:    vn -> vP, MFMA-B-fragment order
//   6. attn v6:   32-row q-tile, 8 waves, k-sliced (unchanged)
//   7. gemm8p<f32>: out = y @ wpT^T + b_proj
//
// Workspace (88 MiB, unchanged):
//   [0,16M)   xh -> vP ; [16M,32M) qn ; [32M,48M) kn -> y ; [48M,64M) vn
//   [64M,80M) kP ; [80M,86M) waT ; [86M,88M) wpT

typedef _Float16 half8 __attribute__((ext_vector_type(8)));
typedef _Float16 half4_t __attribute__((ext_vector_type(4)));
typedef float floatx4 __attribute__((ext_vector_type(4)));

__device__ __forceinline__ void gl2lds16(const void* gsrc, void* lds) {
    __builtin_amdgcn_global_load_lds(
        (const __attribute__((address_space(1))) unsigned int*)gsrc,
        (__attribute__((address_space(3))) unsigned int*)lds,
        16, 0, 0);
}

// ---------------- elementwise convert fp32 -> fp16 ----------------
__global__ __launch_bounds__(256) void conv_x(const float4* __restrict__ in,
                                              _Float16* __restrict__ out, int n4) {
    int idx = blockIdx.x * blockDim.x + threadIdx.x;
    int stride = gridDim.x * blockDim.x;
    for (int i = idx; i < n4; i += stride) {
        float4 v = in[i];
        half4_t h = { (_Float16)v.x, (_Float16)v.y, (_Float16)v.z, (_Float16)v.w };
        *(half4_t*)(out + (size_t)i * 4) = h;
    }
}

// ------------- transpose + convert: out[n][k] = in[k][n] ----------
__global__ __launch_bounds__(256) void tconv(const float* __restrict__ in,
                                             _Float16* __restrict__ out, int R, int C) {
    __shared__ _Float16 t[64 * 65];
    int bx = blockIdx.x, by = blockIdx.y;
#pragma unroll
    for (int it = 0; it < 16; ++it) {
        int idx = it * 256 + threadIdx.x;
        int r = idx >> 6, c = idx & 63;
        t[c * 65 + r] = (_Float16)in[(size_t)(by * 64 + r) * C + bx * 64 + c];
    }
    __syncthreads();
#pragma unroll
    for (int it = 0; it < 16; ++it) {
        int idx = it * 256 + threadIdx.x;
        int rn = idx >> 6, ck = idx & 63;
        out[(size_t)(bx * 64 + rn) * R + by * 64 + ck] = t[rn * 65 + ck];
    }
}

// ------------- pack K into A-fragment order -------------
__global__ __launch_bounds__(256) void pack_k(const _Float16* __restrict__ kn,
                                              _Float16* __restrict__ kP) {
    int cid = blockIdx.x * 256 + threadIdx.x;
    int lane = cid & 63, half = (cid >> 6) & 1, kb = (cid >> 7) & 63, bh = cid >> 13;
    int l15 = lane & 15, quad = lane >> 4;
    int b = bh >> 4, h = bh & 15;
    int t = kb * 16 + l15, d = half * 32 + quad * 8;
    half8 v = *(const half8*)(kn + (size_t)(b * 1024 + t) * 1024 + h * 64 + d);
    *(half8*)(kP + (size_t)cid * 8) = v;
}

// ------------- pack V (transposed) into B-fragment order -------------
__global__ __launch_bounds__(256) void pack_v(const _Float16* __restrict__ vn,
                                              _Float16* __restrict__ vP) {
    __shared__ _Float16 s[32][72];
    int kbv = blockIdx.x, bh = blockIdx.y;
    int b = bh >> 4, h = bh & 15;
    int tid = threadIdx.x;
    {
        int row = tid >> 3, piece = tid & 7;
        *(half8*)&s[row][piece * 8] =
            *(const half8*)(vn + (size_t)(b * 1024 + kbv * 32 + row) * 1024 + h * 64 + piece * 8);
    }
    __syncthreads();
    {
        int l15v = tid & 15, quad = (tid >> 4) & 3, cf = tid >> 6;
        half8 o;
#pragma unroll
        for (int j = 0; j < 8; ++j) o[j] = s[quad * 8 + j][cf * 16 + l15v];
        *(half8*)(vP + ((size_t)(bh * 32 + kbv) * 256 + tid) * 8) = o;
    }
}

// ================= 8-phase pipelined GEMM: C(MxN) = A(MxK) * BT(NxK)^T + bias =================
// BM=256, BN=128, BK=64, K=1024 fixed (16 K-tiles, 8 iters x 2 tiles).
// 512 threads = 8 waves (4M x 2N), per-wave output 64x64 (acc 4x4 frags, 64 VGPR).
// LDS 96 KiB: A = 2buf x 256rows x 64k fp16 (32KB/buf) @0 ; B = 2buf x 128 x 64 (16KB/buf) @65536.
// XOR-swizzle (T2): storage byte(row, slot q) = row*128 + ((q ^ (row&7))*16), q = k/8.
//   -> ds_read_b128 of a fragment column is conflict-free (8 slots x 8 lanes covers 32 banks/cyc).
//   global_load_lds writes linearly; source address is pre-inverse-swizzled (rule #21).
// Tile parity is static: even K-tiles always buf0, odd always buf1.
// Phase schedule per iter (tiles t=2i in buf0 @P1-4, t+1 in buf1 @P5-8); quadrant order per tile:
//   Pa:(rg0,cg0) Pb:(rg0,cg1) Pc:(rg1,cg1) Pd:(rg1,cg0)  => A dead after Pc, B dead after Pb.
// Stage slots (one half-tile/phase; region provably dead at issue):
//   P1:A0(t+1)->Ab1  P2:A1(t+1)->Ab1  P3:B0(t+2)->Bb0  P4:B1(t+2)->Bb0
//   P5:A0(t+2)->Ab0  P6:A1(t+2)->Ab0  P7:B0(t+3)->Bb1  P8:B1(t+3)->Bb1
// Loads/thread: A-half=2, B-half=1 -> 12/iter. vmcnt(2) at P4 (guarantees A(t+1),B(t+1) landed;
// leaves P3+P4 = 2 in flight) and at P8 (guarantees A(t+2),B(t+2); leaves P7+P8). Never vmcnt(0)
// in the loop; raw s_barrier so the compiler doesn't re-insert the drain.
// Prologue: stage A(0),B(0),B(1) (8 loads), vmcnt(2) [leaves B(1) in flight = steady state], barrier.

#define GBAR __builtin_amdgcn_s_barrier()
#define WLGKM do { asm volatile("s_waitcnt lgkmcnt(0)" ::: "memory"); } while (0)
#define WVM2  do { asm volatile("s_waitcnt vmcnt(2)"   ::: "memory"); } while (0)

#define LDA(buf, rg)                                                                          \
    do {                                                                                      \
        _Pragma("unroll") for (int i = 0; i < 2; ++i) {                                       \
            int r_ = wm * 64 + ((rg) * 2 + i) * 16 + l15;                                     \
            _Pragma("unroll") for (int kk = 0; kk < 2; ++kk)                                  \
                a[i][kk] = *(const half8*)(sA + (buf) * 32768 + r_ * 128 +                    \
                                           ((((kk << 2) + quad) ^ (r_ & 7)) << 4));           \
        }                                                                                     \
    } while (0)

#define LDB(buf, cg, bb)                                                                      \
    do {                                                                                      \
        _Pragma("unroll") for (int j = 0; j < 2; ++j) {                                       \
            int r_ = wn * 64 + ((cg) * 2 + j) * 16 + l15;                                     \
            _Pragma("unroll") for (int kk = 0; kk < 2; ++kk)                                  \
                bb[j][kk] = *(const half8*)(sB + (buf) * 16384 + r_ * 128 +                   \
                                            ((((kk << 2) + quad) ^ (r_ & 7)) << 4));          \
        }                                                                                     \
    } while (0)

#define MMA(rg, cg, bb)                                                                       \
    do {                                                                                      \
        __builtin_amdgcn_s_setprio(1);                                                        \
        _Pragma("unroll") for (int kk = 0; kk < 2; ++kk)                                      \
            _Pragma("unroll") for (int i = 0; i < 2; ++i)                                     \
                _Pragma("unroll") for (int j = 0; j < 2; ++j)                                  \
                    acc[(rg) * 2 + i][(cg) * 2 + j] = __builtin_amdgcn_mfma_f32_16x16x32_f16( \
                        a[i][kk], bb[j][kk], acc[(rg) * 2 + i][(cg) * 2 + j], 0, 0, 0);       \
        __builtin_amdgcn_s_setprio(0);                                                        \
    } while (0)

template <bool SPLIT3>
__global__ __launch_bounds__(512, 2) void gemm8p(const _Float16* __restrict__ A,
                                                 const _Float16* __restrict__ BT,
                                                 const float* __restrict__ bias,
                                                 void* __restrict__ o0, void* __restrict__ o1,
                                                 void* __restrict__ o2, int N) {
    __shared__ __attribute__((aligned(16))) char lds[98304];
    char* sA = lds;           // + buf*32768  (+ half*16384 on stage side)
    char* sB = lds + 65536;   // + buf*16384  (+ half*8192  on stage side)
    int tid = threadIdx.x;
    int W = tid >> 6, lane = tid & 63, quad = lane >> 4, l15 = lane & 15;
    int wm = W >> 1, wn = W & 1;
    int m0 = blockIdx.y * 256, n0 = blockIdx.x * 128;

    // --- staging: linear LDS dest, inverse-swizzled global source ---
    auto stA = [&](int buf, int half, int k0) {
#pragma unroll
        for (int rnd = 0; rnd < 2; ++rnd) {
            int c = rnd * 512 + tid;                // chunk id within 16KB half
            int row = c >> 3;
            int q = (c & 7) ^ (row & 7);
            const _Float16* src = A + (size_t)(m0 + half * 128 + row) * 1024 + k0 + q * 8;
            int off = __builtin_amdgcn_readfirstlane(buf * 32768 + half * 16384 +
                                                     rnd * 8192 + (W << 10));
            gl2lds16(src, sA + off);
        }
    };
    auto stB = [&](int buf, int half, int k0) {
        int row = tid >> 3;                          // 64 rows per half, 1 round
        int q = (tid & 7) ^ (row & 7);
        const _Float16* src = BT + (size_t)(n0 + half * 64 + row) * 1024 + k0 + q * 8;
        int off = __builtin_amdgcn_readfirstlane(buf * 16384 + half * 8192 + (W << 10));
        gl2lds16(src, sB + off);
    };

    half8 a[2][2], b0[2][2], b1[2][2];
    floatx4 acc[4][4] = {};

    // --- prologue: A(0),B(0) -> buf0; B(1) -> buf1 ---
    stA(0, 0, 0); stA(0, 1, 0);
    stB(0, 0, 0); stB(0, 1, 0);
    stB(1, 0, 64); stB(1, 1, 64);
    WVM2;       // A(0),B(0) landed; B(1)'s 2 loads in flight
    GBAR;

#pragma unroll 1
    for (int t = 0; t < 16; t += 2) {
        int k1 = (t + 1) << 6;                  // t+1 <= 15, always valid
        int k2 = ((t + 2) & 15) << 6;           // wraps on last iter: garbage into dead bufs
        int k3 = ((t + 3) & 15) << 6;
        // ---- tile t (buf0) ----
        // P1
        LDA(0, 0); LDB(0, 0, b0); stA(1, 0, k1);
        GBAR; WLGKM; MMA(0, 0, b0); GBAR;
        // P2
        LDB(0, 1, b1); stA(1, 1, k1);
        GBAR; WLGKM; MMA(0, 1, b1); GBAR;
        // P3
        LDA(0, 1); stB(0, 0, k2);
        GBAR; WLGKM; MMA(1, 1, b1); GBAR;
        // P4
        stB(0, 1, k2); WVM2;
        GBAR; WLGKM; MMA(1, 0, b0); GBAR;
        // ---- tile t+1 (buf1) ----
        // P5
        LDA(1, 0); LDB(1, 0, b0); stA(0, 0, k2);
        GBAR; WLGKM; MMA(0, 0, b0); GBAR;
        // P6
        LDB(1, 1, b1); stA(0, 1, k2);
        GBAR; WLGKM; MMA(0, 1, b1); GBAR;
        // P7
        LDA(1, 1); stB(1, 0, k3);
        GBAR; WLGKM; MMA(1, 1, b1); GBAR;
        // P8
        stB(1, 1, k3); WVM2;
        GBAR; WLGKM; MMA(1, 0, b0); GBAR;
    }

    // --- epilogue: C-write straight from acc (no LDS use; trailing stages are dead writes) ---
    _Float16* hbase = nullptr;
    if (SPLIT3) {
        int sec = n0 >> 10;   // BN=128 tiles never straddle 1024 boundaries
        hbase = (_Float16*)(sec == 0 ? o0 : (sec == 1 ? o1 : o2));
    }
#pragma unroll
    for (int cf = 0; cf < 4; ++cf) {
        int gn = n0 + wn * 64 + cf * 16 + l15;
        float bv = bias[gn];
        int cn = gn & 1023;
#pragma unroll
        for (int rf = 0; rf < 4; ++rf) {
            int gmBase = m0 + wm * 64 + rf * 16 + quad * 4;
#pragma unroll
            for (int r = 0; r < 4; ++r) {
                float v = acc[rf][cf][r] + bv;
                if (SPLIT3) hbase[(size_t)(gmBase + r) * 1024 + cn] = (_Float16)v;
                else        ((float*)o0)[(size_t)(gmBase + r) * N + gn] = v;
            }
        }
    }
}

// ------------------------------- attention v6 (unchanged) -------------------------------
__device__ __forceinline__ int esw(int row, int colByte) {
    return row * 2048 + (colByte ^ ((row & 7) << 4));
}

__global__ __launch_bounds__(512, 4) void attn(const _Float16* __restrict__ qn,
                                               const _Float16* __restrict__ kP,
                                               const _Float16* __restrict__ vP,
                                               _Float16* __restrict__ y) {
    __shared__ __attribute__((aligned(16))) _Float16 E[32 * 1024];
    __shared__ float lsum[8][32];
    char* Eb = (char*)E;
    int tid = threadIdx.x;
    int W = tid >> 6, lane = tid & 63, quad = lane >> 4, l15 = lane & 15;
    int qt = blockIdx.x, bh = blockIdx.y;
    int b = bh >> 4, h = bh & 15;
    int q0 = qt * 32;

    half8 bq[2][2];
#pragma unroll
    for (int nf = 0; nf < 2; ++nf)
#pragma unroll
        for (int ks = 0; ks < 2; ++ks)
            bq[nf][ks] = *(const half8*)(qn + (size_t)(b * 1024 + q0 + nf * 16 + l15) * 1024 +
                                         h * 64 + ks * 32 + quad * 8);

    float lpart[2] = {0.f, 0.f};
#pragma unroll 4
    for (int mt = 0; mt < 8; ++mt) {
        int kb = W * 8 + mt;
        const _Float16* kp = kP + ((size_t)(bh * 64 + kb) * 128 + lane) * 8;
        half8 ak0 = *(const half8*)(kp);
        half8 ak1 = *(const half8*)(kp + 512);
#pragma unroll
        for (int nf = 0; nf < 2; ++nf) {
            floatx4 s = {};
            s = __builtin_amdgcn_mfma_f32_16x16x32_f16(ak0, bq[nf][0], s, 0, 0, 0);
            s = __builtin_amdgcn_mfma_f32_16x16x32_f16(ak1, bq[nf][1], s, 0, 0, 0);
            half4_t h4;
#pragma unroll
            for (int r = 0; r < 4; ++r) {
                float e = __expf(fminf(s[r] * 0.125f, 10.0f));
                lpart[nf] += e;
                h4[r] = (_Float16)e;
            }
            int q = nf * 16 + l15;
            int kbyte = (W * 128 + mt * 16 + quad * 4) * 2;
            *(half4_t*)(Eb + q * 2048 + (kbyte ^ ((q & 7) << 4))) = h4;
        }
    }
#pragma unroll
    for (int nf = 0; nf < 2; ++nf) {
        lpart[nf] += __shfl_xor(lpart[nf], 16);
        lpart[nf] += __shfl_xor(lpart[nf], 32);
    }
    if (lane < 16) {
        lsum[W][l15] = lpart[0];
        lsum[W][16 + l15] = lpart[1];
    }
    __syncthreads();

    half8 inv8[2], t8, z8;
#pragma unroll
    for (int j = 0; j < 8; ++j) { t8[j] = (_Float16)(-0.001f); z8[j] = (_Float16)0.f; }
#pragma unroll
    for (int rf = 0; rf < 2; ++rf) {
        float l = 0.f;
#pragma unroll
        for (int w = 0; w < 8; ++w) l += lsum[w][rf * 16 + l15];
        _Float16 invh = (_Float16)(1.0f / l);
#pragma unroll
        for (int j = 0; j < 8; ++j) inv8[rf][j] = invh;
    }

    floatx4 acc[2][4] = {};
#pragma unroll
    for (int kt = 0; kt < 4; ++kt) {
        int kk = W * 128 + kt * 32;
        half8 ap[2];
#pragma unroll
        for (int rf = 0; rf < 2; ++rf) {
            ap[rf] = *(const half8*)(Eb + esw(rf * 16 + l15, (kk + quad * 8) * 2));
            ap[rf] = ap[rf] * inv8[rf] + t8;
            ap[rf] = __builtin_elementwise_max(ap[rf], z8);
        }
        const _Float16* vbase = vP + ((size_t)(bh * 32 + (W * 4 + kt)) * 256 + lane) * 8;
        half8 bv[4];
#pragma unroll
        for (int cf = 0; cf < 4; ++cf)
            bv[cf] = *(const half8*)(vbase + cf * 512);
#pragma unroll
        for (int rf = 0; rf < 2; ++rf)
#pragma unroll
            for (int cf = 0; cf < 4; ++cf)
                acc[rf][cf] = __builtin_amdgcn_mfma_f32_16x16x32_f16(ap[rf], bv[cf], acc[rf][cf], 0, 0, 0);
    }
    __syncthreads();

    float* red = (float*)E;
#pragma unroll
    for (int rf = 0; rf < 2; ++rf)
#pragma unroll
        for (int cf = 0; cf < 4; ++cf)
#pragma unroll
            for (int r = 0; r < 4; ++r)
                red[W * 2048 + (rf * 16 + quad * 4 + r) * 64 + cf * 16 + l15] = acc[rf][cf][r];
    __syncthreads();
    {
        int e4 = tid * 4;
        int r = e4 >> 6, c = e4 & 63;
        floatx4 s = {};
#pragma unroll
        for (int w = 0; w < 8; ++w) s += *(const floatx4*)(red + w * 2048 + e4);
        half4_t hv = { (_Float16)s[0], (_Float16)s[1], (_Float16)s[2], (_Float16)s[3] };
        *(half4_t*)(y + (size_t)(b * 1024 + q0 + r) * 1024 + h * 64 + c) = hv;
    }
}

// ------------------------------- launcher -------------------------------
extern "C" void kernel_launch(void* const* d_in, const int* in_sizes, int n_in,
                              void* d_out, int out_size, void* d_ws, size_t ws_size,
                              hipStream_t stream) {
    const float* x  = (const float*)d_in[0];
    const float* wa = (const float*)d_in[1];
    const float* ba = (const float*)d_in[2];
    const float* wp = (const float*)d_in[3];
    const float* bp = (const float*)d_in[4];
    float* out = (float*)d_out;

    char* ws = (char*)d_ws;
    _Float16* xh  = (_Float16*)(ws);                    // [0,16M)  dead after gemm1
    _Float16* vP  = (_Float16*)(ws);                    //   -> vP (pack_v onward)
    _Float16* qn  = (_Float16*)(ws + 16777216);         // [16M,32M) live through attn
    _Float16* kn  = (_Float16*)(ws + 33554432);         // [32M,48M) dead after pack_k
    _Float16* y   = (_Float16*)(ws + 33554432);         //   -> y (attn onward)
    _Float16* vn  = (_Float16*)(ws + 50331648);         // [48M,64M) dead after pack_v
    _Float16* kP  = (_Float16*)(ws + 67108864);         // [64M,80M)
    _Float16* waT = (_Float16*)(ws + 83886080);         // [80M,86M)
    _Float16* wpT = (_Float16*)(ws + 90177536);         // [86M,88M)

    conv_x<<<4096, 256, 0, stream>>>((const float4*)x, xh, 8388608 / 4);
    tconv<<<dim3(48, 16), 256, 0, stream>>>(wa, waT, 1024, 3072);
    tconv<<<dim3(16, 16), 256, 0, stream>>>(wp, wpT, 1024, 1024);
    gemm8p<true><<<dim3(24, 32), 512, 0, stream>>>(xh, waT, ba, (void*)qn, (void*)kn, (void*)vn, 3072);
    pack_k<<<4096, 256, 0, stream>>>(kn, kP);
    pack_v<<<dim3(32, 128), 256, 0, stream>>>(vn, vP);
    attn<<<dim3(32, 128), 512, 0, stream>>>(qn, kP, vP, y);
    gemm8p<false><<<dim3(8, 32), 512, 0, stream>>>(y, wpT, bp, (void*)out, nullptr, nullptr, 1024);
}